// Round 9
// baseline (129.811 us; speedup 1.0000x reference)
//
#include <hip/hip_runtime.h>

#define B_    512
#define IN_   256
#define H_    512
#define OUT_  64
#define NDEATH (B_ - 1)
#define NSORT  512          // NDEATH padded to pow2 for bitonic sort / bsearch
#define RTOL_ 1e-6
#define ATOL_ 1e-8
#define NTHR  512           // 8 waves/block -> 2 waves/SIMD

typedef __attribute__((ext_vector_type(4))) double d4_t;

// ---------------------------------------------------------------------------
// LDS-only barrier: lgkmcnt(0)+s_barrier. Global prefetches ride across.
// ---------------------------------------------------------------------------
__device__ __forceinline__ void lbar() {
    asm volatile("s_waitcnt lgkmcnt(0)" ::: "memory");
    __builtin_amdgcn_s_barrier();
    asm volatile("" ::: "memory");
}

// ---------------------------------------------------------------------------
// per-block: bitonic-sort deaths into LDS, emit sorted tolerance windows.
// 512 threads (1 elem/thread fill, 256 comparators/round).
// ---------------------------------------------------------------------------
__device__ void sort_windows(const float* __restrict__ deaths,
                             double* sd, double* slo, double* shi, int t) {
    if (t < NSORT) sd[t] = (t < NDEATH) ? (double)deaths[t] : 1e300;
    __syncthreads();
    for (int k = 2; k <= NSORT; k <<= 1) {
        for (int j = k >> 1; j > 0; j >>= 1) {
            if (t < 256) {
                int l = ((t & ~(j - 1)) << 1) | (t & (j - 1));   // pair (l, l+j)
                int p = l + j;
                bool up = ((l & k) == 0);
                double a = sd[l], b = sd[p];
                if ((a > b) == up) { sd[l] = b; sd[p] = a; }
            }
            __syncthreads();
        }
    }
    if (t < NSORT) {
        double d = sd[t];
        double w = ATOL_ + RTOL_ * fabs(d);
        slo[t] = d - w;
        shi[t] = d + w;
    }
    __syncthreads();
}

// ---------------------------------------------------------------------------
// f64 MFMA GEMM phase, R22: FULL-STRIP A IN LDS, BARRIER-FREE K-LOOP.
// The block's whole 32-row A strip (32 x K doubles, <=132 KB padded) is staged
// ONCE at phase start (batched 32 loads -> 32 ds_writes per thread, one lbar).
// The K-loop is then pure {ds_read A, MFMA, direct-global B ring} per wave:
// no per-iter barrier convoy, no lgkm drain, no ds_writes -- waves drift
// freely and 2 waves/SIMD co-hide latency. Split-K x2 across wavegroups,
// c4a/c4b chains, cEx exchange: accumulation order byte-identical to the
// verified R16 math -> bit-identical numerics.
// ---------------------------------------------------------------------------
template <typename TIN, bool RELU, int N, int K>
__device__ void gemm_dev(const TIN* __restrict__ A, const float* __restrict__ W,
                         const float* __restrict__ bias, double* __restrict__ C,
                         int tile, int t, double* __restrict__ lds) {
    constexpr int nkt = K >> 6;           // 32-k chunks per K-half
    double* AsB = lds;                    // [2][nkt][32][33]
    double* cEx = lds + 2 * nkt * 32 * 33;// [4][16][17]

    const int lane  = t & 63;
    const int wave4 = (t >> 6) & 3;
    const int w2    = t >> 8;             // wavegroup = K-half
    const int tg    = t & 255;
    const int wm    = wave4 & 1, wn = wave4 >> 1;
    constexpr int nbx = N >> 5;
    const int row0  = (tile / nbx) << 5;
    const int col0  = (tile % nbx) << 5;

    const int akk   = tg & 31;            // k within 32-chunk
    const int amm   = tg >> 5;            // base row (rows amm+8p)
    const int kbase = w2 * (K >> 1);

    const int mrow  = wm * 16 + (lane & 15);
    const int ncol  = wn * 16 + (lane & 15);
    const int kq    = lane >> 4;

    float br[3][8];
    auto load_b = [&](int rs, int kt) {
        const int k0 = kbase + (kt << 5);
        const float* wp = W + (size_t)(k0 + kq) * N + col0 + ncol;
        #pragma unroll
        for (int ks = 0; ks < 8; ++ks)
            br[rs][ks] = wp[(size_t)(4 * ks) * N];
    };
    load_b(0, 0);
    if (nkt > 1) load_b(1, 1);
    if (nkt > 2) load_b(2, 2);

    // full-strip A staging: all loads issued back-to-back, then all writes
    TIN tmp[nkt * 4];
    #pragma unroll
    for (int q = 0; q < nkt; ++q)
        #pragma unroll
        for (int p = 0; p < 4; ++p)
            tmp[q * 4 + p] =
                A[(size_t)(row0 + amm + 8 * p) * K + kbase + (q << 5) + akk];
    #pragma unroll
    for (int q = 0; q < nkt; ++q)
        #pragma unroll
        for (int p = 0; p < 4; ++p)
            AsB[((w2 * nkt + q) * 32 + akk) * 33 + amm + 8 * p] =
                (double)tmp[q * 4 + p];
    lbar();   // the ONLY barrier before the K-loop

    d4_t c4a = {0.0, 0.0, 0.0, 0.0};
    d4_t c4b = {0.0, 0.0, 0.0, 0.0};

    #pragma unroll
    for (int kt = 0; kt < nkt; ++kt) {
        const int rs = kt % 3;
        const double* ap = &AsB[(size_t)((w2 * nkt + kt) * 32) * 33];
        __builtin_amdgcn_s_setprio(1);
        #pragma unroll
        for (int ks = 0; ks < 4; ++ks) {
            double av = ap[(ks * 4 + kq) * 33 + mrow];
            c4a = __builtin_amdgcn_mfma_f64_16x16x4f64(av, (double)br[rs][ks],
                                                       c4a, 0, 0, 0);
        }
        #pragma unroll
        for (int ks = 4; ks < 8; ++ks) {
            double av = ap[(ks * 4 + kq) * 33 + mrow];
            c4b = __builtin_amdgcn_mfma_f64_16x16x4f64(av, (double)br[rs][ks],
                                                       c4b, 0, 0, 0);
        }
        __builtin_amdgcn_s_setprio(0);
        if (kt + 3 < nkt) load_b(rs, kt + 3);   // refill consumed ring slot
    }

    d4_t c4 = c4a + c4b;

    // combine K-half partials: wg1 publishes, wg0 adds + epilogue.
    const int r4 = (lane >> 4) * 4;
    if (w2 == 1) {
        #pragma unroll
        for (int r = 0; r < 4; ++r)
            cEx[(wave4 * 16 + r4 + r) * 17 + (lane & 15)] = c4[r];
    }
    lbar();
    if (w2 == 0) {
        #pragma unroll
        for (int r = 0; r < 4; ++r) {
            int row = row0 + wm * 16 + r4 + r;
            int col = col0 + wn * 16 + (lane & 15);
            double v = c4[r] + cEx[(wave4 * 16 + r4 + r) * 17 + (lane & 15)]
                     + (double)bias[col];
            if (RELU) v = v > 0.0 ? v : 0.0;
            C[(size_t)row * N + col] = v;
        }
    }
}

// XCD-local tile mapping (R19): blocks with equal bid&7 share an XCD ->
// a 16-block "group" g reads one 32-row A-strip from the same L2.
__device__ __forceinline__ int tile_map(int bid) {
    const int g = (bid & 7) | ((bid >> 7) << 3);
    const int c = (bid >> 3) & 15;
    return g * 16 + c;
}

// ---------------------------------------------------------------------------
// dispatch 1: GEMM1 (256 tiles, K=256) + sort block (bid==256).
// LDS: 2*4*32*33 + 4*16*17 = 9536 dbl = 76.3 KB (sort aliases the front).
// ---------------------------------------------------------------------------
__global__ __launch_bounds__(NTHR, 2) void g1s_k(
    const float* __restrict__ batch, const float* __restrict__ W1,
    const float* __restrict__ b1, double* __restrict__ hA,
    const float* __restrict__ deaths, double* __restrict__ wbc) {
    __shared__ double lds[2 * 4 * 32 * 33 + 4 * 16 * 17];
    const int t = threadIdx.x, bid = blockIdx.x;
    if (bid == 256) {
        double* sd  = lds;
        double* slo = lds + NSORT;
        double* shi = lds + 2 * NSORT;
        sort_windows(deaths, sd, slo, shi, t);
        if (t < NSORT) {
            wbc[t]         = slo[t];
            wbc[NSORT + t] = shi[t];
        }
        return;
    }
    gemm_dev<float, true, H_, IN_>(batch, W1, b1, hA, tile_map(bid), t, lds);
}

// dispatches 2,3: full 512x512x512 GEMMs.
// LDS: 2*8*32*33 + 4*16*17 = 17984 dbl = 143.9 KB (1 block/CU).
template <bool RELU>
__global__ __launch_bounds__(NTHR, 2) void gemm_k(
    const double* __restrict__ A, const float* __restrict__ W,
    const float* __restrict__ bias, double* __restrict__ C) {
    __shared__ double lds[2 * 8 * 32 * 33 + 4 * 16 * 17];
    gemm_dev<double, RELU, H_, H_>(A, W, bias, C, tile_map(blockIdx.x),
                                   threadIdx.x, lds);
}

// dispatch 4: Wout GEMM, 32 tiles (512x64 output)
__global__ __launch_bounds__(NTHR, 2) void gout_k(
    const double* __restrict__ hC, const float* __restrict__ Wout,
    const float* __restrict__ bout, double* __restrict__ yv) {
    __shared__ double lds[2 * 8 * 32 * 33 + 4 * 16 * 17];
    gemm_dev<double, false, OUT_, H_>(hC, Wout, bout, yv, blockIdx.x,
                                      threadIdx.x, lds);
}

// ---------------------------------------------------------------------------
// pdist + sorted-window match. Block b: rows b and 510-b (512 pairs, balanced).
// ---------------------------------------------------------------------------
__device__ __forceinline__ double pair_val(const double* __restrict__ yrow_s,
                                           const double* __restrict__ yj,
                                           const double* __restrict__ slo,
                                           const double* __restrict__ shi) {
    double s = 0.0;
    #pragma unroll
    for (int d = 0; d < OUT_; d += 2) {
        double2 v = *(const double2*)(yj + d);
        double d0 = yrow_s[d]     - v.x;
        double d1 = yrow_s[d + 1] - v.y;
        s = fma(d0, d0, s);
        s = fma(d1, d1, s);
    }
    double pd = sqrt(s);
    int pos = 0;
    #pragma unroll
    for (int step = NSORT / 2; step; step >>= 1) {
        if (slo[pos + step - 1] <= pd) pos += step;
    }
    bool m = (pos > 0) && (shi[pos - 1] >= pd);
    return m ? pd : 0.0;
}

__device__ void pdist_dev(const double* __restrict__ y,
                          double* __restrict__ hom_part, int bid, int t,
                          double* yA, double* yB,
                          const double* slo, const double* shi) {
    const int iA = bid;
    const int iB = 510 - bid;     // == iA when bid == 255
    if (t < OUT_)            yA[t]        = y[(size_t)iA * OUT_ + t];
    else if (t < 2 * OUT_)   yB[t - OUT_] = y[(size_t)iB * OUT_ + (t - OUT_)];
    __syncthreads();

    double local = 0.0;
    for (int j = iA + 1 + t; j < B_; j += NTHR)
        local += pair_val(yA, y + (size_t)j * OUT_, slo, shi);
    if (iB != iA)
        for (int j = iB + 1 + t; j < B_; j += NTHR)
            local += pair_val(yB, y + (size_t)j * OUT_, slo, shi);

    for (int off = 32; off; off >>= 1) local += __shfl_down(local, off);
    __shared__ double sw[8];
    int wave = t >> 6, lane = t & 63;
    if (lane == 0) sw[wave] = local;
    __syncthreads();
    if (t == 0) {
        double s = 0.0;
        #pragma unroll
        for (int w = 0; w < 8; ++w) s += sw[w];
        hom_part[bid] = s;
    }
}

// ---------------------------------------------------------------------------
// column c: mean + target-MSE partial + compactness partial -> global slots
// ---------------------------------------------------------------------------
__device__ void mc_dev(const float* __restrict__ target,
                       const double* __restrict__ y,
                       double* __restrict__ t_part, double* __restrict__ c_part,
                       int c, int t) {
    const int wave = t >> 6, lane = t & 63;
    double v = y[(size_t)t * OUT_ + c];
    double s = v;
    for (int off = 32; off; off >>= 1) s += __shfl_down(s, off);
    __shared__ double swm[8];
    __shared__ double smean;
    if (lane == 0) swm[wave] = s;
    __syncthreads();
    if (t == 0) {
        double m = 0.0;
        #pragma unroll
        for (int w = 0; w < 8; ++w) m += swm[w];
        smean = m / (double)B_;
    }
    __syncthreads();
    double m = smean;
    double d = (double)target[(size_t)t * OUT_ + c] - v;
    double t_s = d * d;
    double c_s = fabs(v - m);
    for (int off = 32; off; off >>= 1) {
        t_s += __shfl_down(t_s, off);
        c_s += __shfl_down(c_s, off);
    }
    __shared__ double st[8], sc[8];
    if (lane == 0) { st[wave] = t_s; sc[wave] = c_s; }
    __syncthreads();
    if (t == 0) {
        double ts = 0.0, cs = 0.0;
        #pragma unroll
        for (int w = 0; w < 8; ++w) { ts += st[w]; cs += sc[w]; }
        t_part[c] = ts;
        c_part[c] = cs;
    }
}

// dispatch 5: pdist on 256 blocks; mean/MSE/compactness on blocks 0..63
__global__ __launch_bounds__(NTHR) void pd_k(
    const double* __restrict__ yv, const float* __restrict__ target,
    const double* __restrict__ wbc, double* __restrict__ hom_part,
    double* __restrict__ t_part, double* __restrict__ c_part) {
    __shared__ double slo[NSORT], shi[NSORT];
    __shared__ double yA[OUT_], yB[OUT_];
    const int t = threadIdx.x, bid = blockIdx.x;
    slo[t] = wbc[t];
    shi[t] = wbc[NSORT + t];
    pdist_dev(yv, hom_part, bid, t, yA, yB, slo, shi);   // syncs before use
    if (bid < OUT_) mc_dev(target, yv, t_part, c_part, bid, t);
}

// dispatch 6: final reduction (1 block)
__global__ __launch_bounds__(NTHR) void fin_k(
    const double* __restrict__ hom_part, const double* __restrict__ t_part,
    const double* __restrict__ c_part, float* __restrict__ out) {
    const int t = threadIdx.x;
    double h = 0.0, tp = 0.0, cp = 0.0;
    if (t < 256)  h = hom_part[t];
    if (t < OUT_) { tp = t_part[t]; cp = c_part[t]; }
    for (int off = 32; off; off >>= 1) {
        h  += __shfl_down(h,  off);
        tp += __shfl_down(tp, off);
        cp += __shfl_down(cp, off);
    }
    __shared__ double sh[8], stp[8], scp[8];
    int wave = t >> 6, lane = t & 63;
    if (lane == 0) { sh[wave] = h; stp[wave] = tp; scp[wave] = cp; }
    __syncthreads();
    if (t == 0) {
        double hs = 0.0, ts = 0.0, cs = 0.0;
        #pragma unroll
        for (int w = 0; w < 8; ++w) { hs += sh[w]; ts += stp[w]; cs += scp[w]; }
        out[0] = (float)(ts / (double)(B_ * OUT_) + hs + 0.01 * cs);
    }
}

extern "C" void kernel_launch(void* const* d_in, const int* in_sizes, int n_in,
                              void* d_out, int out_size, void* d_ws, size_t ws_size,
                              hipStream_t stream) {
    const float* batch  = (const float*)d_in[0];
    const float* target = (const float*)d_in[1];
    const float* W1     = (const float*)d_in[2];
    const float* b1     = (const float*)d_in[3];
    const float* W2     = (const float*)d_in[4];
    const float* b2     = (const float*)d_in[5];
    const float* W3     = (const float*)d_in[6];
    const float* b3     = (const float*)d_in[7];
    const float* Wout   = (const float*)d_in[8];
    const float* bout   = (const float*)d_in[9];
    const float* deaths = (const float*)d_in[10];
    float* out = (float*)d_out;

    double* hA       = (double*)d_ws;              // 512*512
    double* hB       = hA + (size_t)B_ * H_;       // 512*512
    double* hC       = hB + (size_t)B_ * H_;       // 512*512
    double* yv       = hC + (size_t)B_ * H_;       // 512*64
    double* hom_part = yv + (size_t)B_ * OUT_;     // 256
    double* t_part   = hom_part + 256;             // 64
    double* c_part   = t_part + OUT_;              // 64
    double* wbc      = c_part + OUT_;              // 1024 doubles (lo|hi)

    g1s_k<<<dim3(257), dim3(NTHR), 0, stream>>>(batch, W1, b1, hA, deaths, wbc);
    gemm_k<true><<<dim3(256), dim3(NTHR), 0, stream>>>(hA, W2, b2, hB);
    gemm_k<true><<<dim3(256), dim3(NTHR), 0, stream>>>(hB, W3, b3, hC);
    gout_k<<<dim3(32), dim3(NTHR), 0, stream>>>(hC, Wout, bout, yv);
    pd_k<<<dim3(256), dim3(NTHR), 0, stream>>>(yv, target, wbc,
                                               hom_part, t_part, c_part);
    fin_k<<<dim3(1), dim3(NTHR), 0, stream>>>(hom_part, t_part, c_part, out);
}

// Round 10
// 124.735 us; speedup vs baseline: 1.0407x; 1.0407x over previous
//
#include <hip/hip_runtime.h>

#define B_    512
#define IN_   256
#define H_    512
#define OUT_  64
#define NDEATH (B_ - 1)
#define NSORT  512          // NDEATH padded to pow2 for bitonic sort / bsearch
#define RTOL_ 1e-6
#define ATOL_ 1e-8
#define NBLK  256
#define NTHR  512           // 8 waves/block -> 2 waves/SIMD

typedef __attribute__((ext_vector_type(4))) double d4_t;

// agent-visible store: relaxed atomic, bypasses L2 -> lands at L3 coherence
// point. No dirty L2 lines => barriers need NO wbl2/inv fences. (R11-verified)
__device__ __forceinline__ void ast(double* p, double v) {
    __hip_atomic_store(p, v, __ATOMIC_RELAXED, __HIP_MEMORY_SCOPE_AGENT);
}
__device__ __forceinline__ double ald(const double* p) {
    return __hip_atomic_load(p, __ATOMIC_RELAXED, __HIP_MEMORY_SCOPE_AGENT);
}
__device__ __forceinline__ unsigned aldu(const unsigned* p) {
    return __hip_atomic_load(p, __ATOMIC_RELAXED, __HIP_MEMORY_SCOPE_AGENT);
}
__device__ __forceinline__ void aadd(unsigned* p) {
    __hip_atomic_fetch_add(p, 1u, __ATOMIC_RELAXED, __HIP_MEMORY_SCOPE_AGENT);
}

// ---------------------------------------------------------------------------
// LDS-only barrier (R15): lgkmcnt(0)+s_barrier. Global prefetches ride across.
// ---------------------------------------------------------------------------
__device__ __forceinline__ void lbar() {
    asm volatile("s_waitcnt lgkmcnt(0)" ::: "memory");
    __builtin_amdgcn_s_barrier();
    asm volatile("" ::: "memory");
}

// ---------------------------------------------------------------------------
// 16-way group barrier (R11-verified). Full __syncthreads REQUIRED: the
// vmcnt(0) drain makes prior ast stores visible before the arrival.
// ---------------------------------------------------------------------------
__device__ __forceinline__ void gbar(unsigned* cnt, unsigned nb) {
    __syncthreads();
    if (threadIdx.x == 0) {
        aadd(cnt);
        while (aldu(cnt) < nb) __builtin_amdgcn_s_sleep(1);
    }
    __syncthreads();
}

// two-level device barrier (R16): 16 parallel group arrivals + 16-way root.
__device__ __forceinline__ void gbar2(unsigned* gslot, unsigned* root,
                                      int leader) {
    __syncthreads();
    if (threadIdx.x == 0) {
        aadd(gslot);
        if (leader) {
            while (aldu(gslot) < 16u) __builtin_amdgcn_s_sleep(1);
            aadd(root);
        }
        while (aldu(root) < 16u) __builtin_amdgcn_s_sleep(1);
    }
    __syncthreads();
}

// ---------------------------------------------------------------------------
// per-block: bitonic-sort deaths into LDS, emit sorted tolerance windows.
// ---------------------------------------------------------------------------
__device__ void sort_windows(const float* __restrict__ deaths,
                             double* sd, double* slo, double* shi, int t) {
    if (t < NSORT) sd[t] = (t < NDEATH) ? (double)deaths[t] : 1e300;
    __syncthreads();
    for (int k = 2; k <= NSORT; k <<= 1) {
        for (int j = k >> 1; j > 0; j >>= 1) {
            if (t < 256) {
                int l = ((t & ~(j - 1)) << 1) | (t & (j - 1));   // pair (l, l+j)
                int p = l + j;
                bool up = ((l & k) == 0);
                double a = sd[l], b = sd[p];
                if ((a > b) == up) { sd[l] = b; sd[p] = a; }
            }
            __syncthreads();
        }
    }
    if (t < NSORT) {
        double d = sd[t];
        double w = ATOL_ + RTOL_ * fabs(d);
        slo[t] = d - w;
        shi[t] = d + w;
    }
    __syncthreads();
}

// ---------------------------------------------------------------------------
// R23: B-ring prefetch (4 x 32-k chunks), hoisted ABOVE the group barrier by
// the caller -- weights are kernel inputs (always ready), so their latency
// overlaps the barrier wait instead of following it.
// ---------------------------------------------------------------------------
template <int N, int K>
__device__ __forceinline__ void prefetchB(const float* __restrict__ W,
                                          int tile, int t, float (&br)[4][8]) {
    const int lane  = t & 63;
    const int wave4 = (t >> 6) & 3;
    const int w2    = t >> 8;
    const int wn    = wave4 >> 1;
    constexpr int nbx = N >> 5;
    const int col0  = (tile % nbx) << 5;
    const int ncol  = wn * 16 + (lane & 15);
    const int kq    = lane >> 4;
    const int kbase = w2 * (K >> 1);
    constexpr int nch = K >> 6;          // 32-k chunks per K-half
    #pragma unroll
    for (int s = 0; s < 4; ++s) {
        if (s < nch) {
            const int k0 = kbase + (s << 5);
            const float* wp = W + (size_t)(k0 + kq) * N + col0 + ncol;
            #pragma unroll
            for (int ks = 0; ks < 8; ++ks)
                br[s][ks] = wp[(size_t)(4 * ks) * N];
        }
    }
}

// ---------------------------------------------------------------------------
// f64 MFMA GEMM phase, R23: KT=64 LDS double-buffer -> HALF the K-loop
// barriers (4+1 vs 8+1 per K=512 phase). Split-K x2 across wavegroups; A
// staged via LDS (depth-2 register ring at 64-k granularity, static indices);
// B ring pre-loaded by caller (slots 0-3), refilled 2 chunks/iter; two
// accumulators. 32-k chunk order and c4a/c4b ks-split identical to the
// verified R16/R20 math -> bit-identical numerics.
// ---------------------------------------------------------------------------
template <typename TIN, bool RELU, int N, int K>
__device__ void gemm_dev(const TIN* __restrict__ A, const float* __restrict__ W,
                         const float* __restrict__ bias, double* __restrict__ C,
                         int tile, int t, double (&As)[2][2][64][33],
                         double (&cEx)[4][16][17], float (&br)[4][8]) {
    const int lane  = t & 63;
    const int wave4 = (t >> 6) & 3;
    const int w2    = t >> 8;            // wavegroup = K-half
    const int tg    = t & 255;
    const int wm    = wave4 & 1, wn = wave4 >> 1;
    constexpr int nbx = N >> 5;
    const int row0  = (tile / nbx) << 5;
    const int col0  = (tile % nbx) << 5;

    const int akk   = tg & 63;           // k within 64-chunk
    const int amm   = tg >> 6;           // base row; rows amm+4p, p=0..7
    const int kbase = w2 * (K >> 1);
    constexpr int nbuf = K >> 7;         // 64-k buffers per half (512->4)
    constexpr int nch  = K >> 6;         // 32-k chunks per half (512->8)

    const int mrow  = wm * 16 + (lane & 15);
    const int ncol  = wn * 16 + (lane & 15);
    const int kq    = lane >> 4;

    TIN ar[2][8];
    auto load_a = [&](int slot, int buf) {
        const int k0 = kbase + (buf << 6);
        #pragma unroll
        for (int p = 0; p < 8; ++p)
            ar[slot][p] = A[(size_t)(row0 + amm + 4 * p) * K + k0 + akk];
    };
    auto stage_a = [&](int slot, int buf) {
        #pragma unroll
        for (int p = 0; p < 8; ++p)
            As[w2][buf & 1][akk][amm + 4 * p] = (double)ar[slot][p];
    };
    auto load_b = [&](int slot, int ch) {
        const int k0 = kbase + (ch << 5);
        const float* wp = W + (size_t)(k0 + kq) * N + col0 + ncol;
        #pragma unroll
        for (int ks = 0; ks < 8; ++ks)
            br[slot][ks] = wp[(size_t)(4 * ks) * N];
    };

    load_a(0, 0);
    if (nbuf > 1) load_a(1, 1);
    stage_a(0, 0);
    lbar();

    d4_t c4a = {0.0, 0.0, 0.0, 0.0};
    d4_t c4b = {0.0, 0.0, 0.0, 0.0};

    #pragma unroll
    for (int it = 0; it < nbuf; ++it) {
        __builtin_amdgcn_s_setprio(1);
        #pragma unroll
        for (int sub = 0; sub < 2; ++sub) {     // 32-chunk ch = 2it+sub, asc
            const int ch = 2 * it + sub;
            const int bs = ch & 3;              // B ring slot
            #pragma unroll
            for (int ks = 0; ks < 4; ++ks) {
                double av = As[w2][it & 1][sub * 32 + ks * 4 + kq][mrow];
                c4a = __builtin_amdgcn_mfma_f64_16x16x4f64(
                          av, (double)br[bs][ks], c4a, 0, 0, 0);
            }
            #pragma unroll
            for (int ks = 4; ks < 8; ++ks) {
                double av = As[w2][it & 1][sub * 32 + ks * 4 + kq][mrow];
                c4b = __builtin_amdgcn_mfma_f64_16x16x4f64(
                          av, (double)br[bs][ks], c4b, 0, 0, 0);
            }
        }
        __builtin_amdgcn_s_setprio(0);
        // refills (all indices compile-time under full unroll)
        if (it + 2 < nbuf) load_a(it & 1, it + 2);
        if (2 * it + 4 < nch) load_b((2 * it + 4) & 3, 2 * it + 4);
        if (2 * it + 5 < nch) load_b((2 * it + 5) & 3, 2 * it + 5);
        if (it + 1 < nbuf) stage_a((it + 1) & 1, it + 1);  // disjoint buffer
        lbar();
    }

    d4_t c4 = c4a + c4b;

    // combine K-half partials: wg1 publishes, wg0 adds + epilogue.
    const int r4 = (lane >> 4) * 4;
    if (w2 == 1) {
        #pragma unroll
        for (int r = 0; r < 4; ++r)
            cEx[wave4][r4 + r][lane & 15] = c4[r];
    }
    lbar();
    if (w2 == 0) {
        #pragma unroll
        for (int r = 0; r < 4; ++r) {
            int row = row0 + wm * 16 + r4 + r;
            int col = col0 + wn * 16 + (lane & 15);
            double v = c4[r] + cEx[wave4][r4 + r][lane & 15] + (double)bias[col];
            if (RELU) v = v > 0.0 ? v : 0.0;
            ast(&C[(size_t)row * N + col], v);
        }
    }
}

// ---------------------------------------------------------------------------
// column c: mean + target-MSE partial + compactness partial -> global slots
// ---------------------------------------------------------------------------
__device__ void mc_dev(const float* __restrict__ target,
                       const double* __restrict__ y,
                       double* __restrict__ t_part, double* __restrict__ c_part,
                       int c, int t) {
    const int wave = t >> 6, lane = t & 63;
    double v = y[(size_t)t * OUT_ + c];
    double s = v;
    for (int off = 32; off; off >>= 1) s += __shfl_down(s, off);
    __shared__ double swm[8];
    __shared__ double smean;
    if (lane == 0) swm[wave] = s;
    __syncthreads();
    if (t == 0) {
        double m = 0.0;
        #pragma unroll
        for (int w = 0; w < 8; ++w) m += swm[w];
        smean = m / (double)B_;
    }
    __syncthreads();
    double m = smean;
    double d = (double)target[(size_t)t * OUT_ + c] - v;
    double t_s = d * d;
    double c_s = fabs(v - m);
    for (int off = 32; off; off >>= 1) {
        t_s += __shfl_down(t_s, off);
        c_s += __shfl_down(c_s, off);
    }
    __shared__ double st[8], sc[8];
    if (lane == 0) { st[wave] = t_s; sc[wave] = c_s; }
    __syncthreads();
    if (t == 0) {
        double ts = 0.0, cs = 0.0;
        #pragma unroll
        for (int w = 0; w < 8; ++w) { ts += st[w]; cs += sc[w]; }
        ast(&t_part[c], ts);
        ast(&c_part[c], cs);
    }
}

// ---------------------------------------------------------------------------
// pdist + sorted-window match. Block b: rows b and 510-b (512 pairs, balanced).
// ---------------------------------------------------------------------------
__device__ __forceinline__ double pair_val(const double* __restrict__ yrow_s,
                                           const double* __restrict__ yj,
                                           const double* __restrict__ slo,
                                           const double* __restrict__ shi) {
    double s = 0.0;
    #pragma unroll
    for (int d = 0; d < OUT_; d += 2) {
        double2 v = *(const double2*)(yj + d);
        double d0 = yrow_s[d]     - v.x;
        double d1 = yrow_s[d + 1] - v.y;
        s = fma(d0, d0, s);
        s = fma(d1, d1, s);
    }
    double pd = sqrt(s);
    int pos = 0;
    #pragma unroll
    for (int step = NSORT / 2; step; step >>= 1) {
        if (slo[pos + step - 1] <= pd) pos += step;
    }
    bool m = (pos > 0) && (shi[pos - 1] >= pd);
    return m ? pd : 0.0;
}

__device__ void pdist_dev(const double* __restrict__ y,
                          double* __restrict__ hom_part, int bid, int t,
                          double* yA, double* yB,
                          const double* slo, const double* shi) {
    const int iA = bid;
    const int iB = 510 - bid;     // == iA when bid == 255
    if (t < OUT_)            yA[t]        = y[(size_t)iA * OUT_ + t];
    else if (t < 2 * OUT_)   yB[t - OUT_] = y[(size_t)iB * OUT_ + (t - OUT_)];
    __syncthreads();

    double local = 0.0;
    for (int j = iA + 1 + t; j < B_; j += NTHR)
        local += pair_val(yA, y + (size_t)j * OUT_, slo, shi);
    if (iB != iA)
        for (int j = iB + 1 + t; j < B_; j += NTHR)
            local += pair_val(yB, y + (size_t)j * OUT_, slo, shi);

    for (int off = 32; off; off >>= 1) local += __shfl_down(local, off);
    __shared__ double sw[8];
    int wave = t >> 6, lane = t & 63;
    if (lane == 0) sw[wave] = local;
    __syncthreads();
    if (t == 0) {
        double s = 0.0;
        #pragma unroll
        for (int w = 0; w < 8; ++w) s += sw[w];
        ast(&hom_part[bid], s);
    }
}

// ---------------------------------------------------------------------------
// single fused persistent kernel, R23: 256 blocks x 512 threads.
// XCD-LOCAL groups (R19): bid -> g=(bid&7)|((bid>>7)<<3), c=(bid>>3)&15;
// group g's 16 blocks share one XCD L2. P0..P2 group-local barriers with the
// NEXT phase's B-ring prefetch hoisted above each barrier; two-level device
// barrier before pdist; two-level finalize with block 0 as fixed finalizer.
// Counters (uints): grp g slot p -> cnt[g*32+p] (p=0..4); pdist root cnt[512];
// finalize root cnt[513]. Window broadcast: wbc[0..511]=lo, wbc[512..1023]=hi.
// ---------------------------------------------------------------------------
__global__ __launch_bounds__(NTHR) void fused_k(
    const float* __restrict__ batch, const float* __restrict__ target,
    const float* __restrict__ W1, const float* __restrict__ b1,
    const float* __restrict__ W2, const float* __restrict__ b2,
    const float* __restrict__ W3, const float* __restrict__ b3,
    const float* __restrict__ Wout, const float* __restrict__ bout,
    const float* __restrict__ deaths, float* __restrict__ out,
    double* __restrict__ hA, double* __restrict__ hB,
    double* __restrict__ hC, double* __restrict__ yv,
    double* __restrict__ hom_part, double* __restrict__ t_part,
    double* __restrict__ c_part, unsigned* __restrict__ cnt,
    double* __restrict__ wbc) {
    const int bid = blockIdx.x;
    const int t   = threadIdx.x;
    const int g   = (bid & 7) | ((bid >> 7) << 3);  // XCD-local group
    const int c   = (bid >> 3) & 15;                // col-tile within group
    const int tile = g * 16 + c;                    // row0=32g, col0=32c
    unsigned* gc  = cnt + g * 32;                   // group counter line

    __shared__ double As[2][2][64][33];             // 67.6 KB
    __shared__ double cEx[4][16][17];               // 8.7 KB
    __shared__ double slo[NSORT], shi[NSORT];       // 8 KB
    __shared__ double yA[OUT_], yB[OUT_];
    double* sd = &As[0][0][0][0];             // sort scratch alias (512 dbl)

    float br[4][8];                           // B ring, lives across barriers

    // P0..P2: three GEMMs; B-ring for phase n+1 prefetched BEFORE gbar n.
    prefetchB<H_, IN_>(W1, tile, t, br);
    gemm_dev<float,  true, H_, IN_>(batch, W1, b1, hA, tile, t, As, cEx, br);
    prefetchB<H_, H_>(W2, tile, t, br);
    gbar(&gc[0], 16);
    gemm_dev<double, true, H_, H_>(hA, W2, b2, hB, tile, t, As, cEx, br);
    prefetchB<H_, H_>(W3, tile, t, br);
    gbar(&gc[1], 16);
    gemm_dev<double, true, H_, H_>(hB, W3, b3, hC, tile, t, As, cEx, br);
    if (c < 2) prefetchB<OUT_, H_>(Wout, g * 2 + c, t, br);
    gbar(&gc[2], 16);

    // P3: Wout tile g*2+c on c<2 (32-row strip g -> group-local dep, same
    // XCD); c>=2 sort. Block (g0,c2) publishes windows for the c<2 blocks.
    if (c < 2) {
        gemm_dev<double, false, OUT_, H_>(hC, Wout, bout, yv, g * 2 + c, t,
                                          As, cEx, br);
    } else {
        sort_windows(deaths, sd, slo, shi, t);
        if (g == 0 && c == 2 && t < NSORT) {
            ast(&wbc[t],         slo[t]);
            ast(&wbc[NSORT + t], shi[t]);
        }
    }

    // two-level device barrier: pdist needs all of yv + window broadcast
    gbar2(&gc[3], &cnt[512], c == 0);
    if (c < 2) {
        if (t < NSORT) {
            slo[t] = ald(&wbc[t]);
            shi[t] = ald(&wbc[NSORT + t]);
        }
        __syncthreads();
    }

    // P4: pdist on all 256 blocks; mean/MSE/compactness on blocks 0..63
    pdist_dev(yv, hom_part, bid, t, yA, yB, slo, shi);
    if (bid < OUT_) mc_dev(target, yv, t_part, c_part, bid, t);

    // P5: two-level finalize arrivals; block 0 is the fixed finalizer.
    __syncthreads();   // vmcnt(0) drain: part stores visible before arrival
    if (t == 0) {
        aadd(&gc[4]);
        if (c == 0) {
            while (aldu(&gc[4]) < 16u) __builtin_amdgcn_s_sleep(1);
            aadd(&cnt[513]);
        }
    }
    if (bid != 0) return;
    if (t == 0)
        while (aldu(&cnt[513]) < 16u) __builtin_amdgcn_s_sleep(1);
    __syncthreads();

    {
        double h = 0.0, tp = 0.0, cp = 0.0;
        if (t < NBLK) h = ald(&hom_part[t]);
        if (t < OUT_) { tp = ald(&t_part[t]); cp = ald(&c_part[t]); }
        for (int off = 32; off; off >>= 1) {
            h  += __shfl_down(h,  off);
            tp += __shfl_down(tp, off);
            cp += __shfl_down(cp, off);
        }
        __shared__ double sh[8], stp[8], scp[8];
        int wave = t >> 6, lane = t & 63;
        if (lane == 0) { sh[wave] = h; stp[wave] = tp; scp[wave] = cp; }
        __syncthreads();
        if (t == 0) {
            double hs = 0.0, ts = 0.0, cs = 0.0;
            #pragma unroll
            for (int w = 0; w < 8; ++w) {
                hs += sh[w]; ts += stp[w]; cs += scp[w];
            }
            out[0] = (float)(ts / (double)(B_ * OUT_) + hs + 0.01 * cs);
        }
    }
}

extern "C" void kernel_launch(void* const* d_in, const int* in_sizes, int n_in,
                              void* d_out, int out_size, void* d_ws, size_t ws_size,
                              hipStream_t stream) {
    const float* batch  = (const float*)d_in[0];
    const float* target = (const float*)d_in[1];
    const float* W1     = (const float*)d_in[2];
    const float* b1     = (const float*)d_in[3];
    const float* W2     = (const float*)d_in[4];
    const float* b2     = (const float*)d_in[5];
    const float* W3     = (const float*)d_in[6];
    const float* b3     = (const float*)d_in[7];
    const float* Wout   = (const float*)d_in[8];
    const float* bout   = (const float*)d_in[9];
    const float* deaths = (const float*)d_in[10];
    float* out = (float*)d_out;

    double* hA       = (double*)d_ws;              // 512*512
    double* hB       = hA + (size_t)B_ * H_;       // 512*512
    double* hC       = hB + (size_t)B_ * H_;       // 512*512
    double* yv       = hC + (size_t)B_ * H_;       // 512*64
    double* hom_part = yv + (size_t)B_ * OUT_;     // 256
    double* t_part   = hom_part + NBLK;            // 64
    double* c_part   = t_part + OUT_;              // 64
    unsigned* cnt    = (unsigned*)(c_part + OUT_); // 576 uints
    double* wbc      = (double*)(cnt + 576);       // 1024 doubles (lo|hi)

    hipMemsetAsync(cnt, 0, 576 * sizeof(unsigned), stream);

    fused_k<<<dim3(NBLK), dim3(NTHR), 0, stream>>>(
        batch, target, W1, b1, W2, b2, W3, b3, Wout, bout, deaths, out,
        hA, hB, hC, yv, hom_part, t_part, c_part, cnt, wbc);
}